// Round 13
// baseline (96.485 us; speedup 1.0000x reference)
//
#include <hip/hip_runtime.h>

#define TILE 16
#define HALO 2
#define LH (TILE + HALO)        // 18 rows: tile + bottom halo (no top halo needed)
#define LW (TILE + 2 * HALO)    // 20 cols -> 360 cells
#define NCELL (LH * LW)
#define HT 512
#define WD 512
#define GRID 2048               // 8 blocks/CU x 256 CUs: fully resident, one batch

typedef _Float16 h2 __attribute__((ext_vector_type(2)));

constexpr float W_IN  = 1.0f / 9.0f + 0.02f;   // 3x3 ring: 1/9 + 0.5/25
constexpr float W_OUT = 0.02f;                 // 5x5 outer ring
// OOB cells staged as zeros -> d = L(1) + E(0) = 1.693869
constexpr float INV_D_OOB = 0.590364f;

__device__ __forceinline__ h2 pk2(float a, float b) {
    return __builtin_bit_cast(h2, __builtin_amdgcn_cvt_pkrtz(a, b));
}
__device__ __forceinline__ h2 hsp(float x) {
    h2 r; r.x = (_Float16)x; r.y = (_Float16)x; return r;
}
__device__ __forceinline__ h2 mkh(float a, float b) {
    h2 r; r.x = (_Float16)a; r.y = (_Float16)b; return r;
}

struct FracH { h2 n, d; };

// Two unordered-pair fractions vs common center, packed in half2 lanes.
// ln(1+u) deg-3 monomial (err<=4.2e-3); e^{-g} deg-3 monomial (err<=1.7e-3), eps folded.
__device__ __forceinline__ FracH pair2h(float cax, h2 cay, h2 caz, h2 caw,
                                        const float4 cb1, const float4 cb2, h2 wv) {
    const float j1 = cax * cb1.x, j2 = cax * cb2.x;
    const h2 J = pk2(j1, j2);
    const h2 U = pk2(__expf(-fabsf(j1)), __expf(-fabsf(j2)));
    const h2 T = pk2(cb1.y, cb2.y);
    const h2 G = pk2(cb1.z, cb2.z);
    const h2 Wb = pk2(cb1.w, cb2.w);
    h2 L = __builtin_elementwise_fma(U, hsp(0.098765f), hsp(-0.370370f));
    L = __builtin_elementwise_fma(L, U, hsp(0.962963f));
    L = __builtin_elementwise_fma(L, U, hsp(0.004231f));
    const h2 LAB = T * cay;
    const h2 mx = __builtin_elementwise_max(J, hsp(0.f));
    h2 m = __builtin_elementwise_fma(-J, LAB, mx);
    m = m + L;
    const h2 GG = G * caz;
    h2 E = __builtin_elementwise_fma(GG, hsp(-0.101088f), hsp(0.454898f));
    E = __builtin_elementwise_fma(E, GG, hsp(-0.985612f));
    E = __builtin_elementwise_fma(E, GG, hsp(0.998280f));
    FracH r;
    r.d = m + E;
    r.n = (Wb + caw) * wv;
    return r;
}

__device__ __forceinline__ FracH mergeh(FracH a, FracH b) {
    FracH r;
    r.n = __builtin_elementwise_fma(a.n, b.d, a.d * b.n);
    r.d = a.d * b.d;
    return r;
}

struct Pre { float p0, t0, p1, t1; bool v0, v1; };

__device__ __forceinline__ Pre prefetch_tile(const float* __restrict__ pred,
                                             const float* __restrict__ targ,
                                             int t, int tid) {
    const int b = t >> 10;
    const int r = t & 1023;
    const int ty0 = (r >> 5) << 4;
    const int tx0 = (r & 31) << 4;
    const float* pb = pred + ((size_t)b << 18);
    const float* tb = targ + ((size_t)b << 18);
    Pre o; o.p0 = 0.f; o.t0 = 0.f; o.p1 = 0.f; o.t1 = 0.f;
    {   // slot 0: cell idx = tid (tid < 256 < 360)
        const int cy = tid / LW, cx = tid - cy * LW;
        const int gy = ty0 + cy, gx = tx0 + cx - HALO;
        o.v0 = ((unsigned)gx < (unsigned)WD) && (gy < HT);
        if (o.v0) { const int gi = (gy << 9) + gx; o.p0 = pb[gi]; o.t0 = tb[gi]; }
    }
    {   // slot 1: cell idx = tid + 256 (only tid < 104)
        const int idx = tid + 256;
        const int cy = idx / LW, cx = idx - cy * LW;
        const int gy = ty0 + cy, gx = tx0 + cx - HALO;
        o.v1 = (idx < NCELL) && ((unsigned)gx < (unsigned)WD) && (gy < HT);
        if (o.v1) { const int gi = (gy << 9) + gx; o.p1 = pb[gi]; o.t1 = tb[gi]; }
    }
    return o;
}

__device__ __forceinline__ float4 make_cell(float p, float t, bool valid) {
    float4 c = make_float4(0.f, 0.f, 0.f, 0.f);
    if (valid) {
        const float en = __expf(-fabsf(p));
        const float inv = __builtin_amdgcn_rcpf(1.f + en);
        const float g = (p >= 0.f) ? inv : en * inv;          // sigmoid(p)
        const float L = fmaf(fmaf(fmaf(0.098765f, en, -0.370370f), en,
                                  0.962963f), en, 0.004231f);
        const float bce = fmaf(-p, t, fmaxf(p, 0.f)) + L;
        c = make_float4(p, t, g, bce);
    }
    return c;
}

__global__ __launch_bounds__(256) void scloss_main(
    const float* __restrict__ pred, const float* __restrict__ target,
    float* __restrict__ out, int total_tiles, double inv_cnt) {
    __shared__ float4 sh[2][NCELL];   // double buffer

    const int tid = threadIdx.x;
    float acc = 0.f;

    constexpr int pdy[12] = {0, 0, 1, 1, 1, 1, 1, 2, 2, 2, 2, 2};
    constexpr int pdx[12] = {1, 2, -2, -1, 0, 1, 2, -2, -1, 0, 1, 2};
    constexpr float pw12[12] = {W_IN, W_OUT, W_OUT, W_IN, W_IN, W_IN,
                                W_OUT, W_OUT, W_OUT, W_OUT, W_OUT, W_OUT};

    Pre cur = prefetch_tile(pred, target, blockIdx.x, tid);

    int buf = 0;
    for (int t = blockIdx.x; t < total_tiles; t += GRID, buf ^= 1) {
        // Stage current tile from prefetched registers.
        sh[buf][tid] = make_cell(cur.p0, cur.t0, cur.v0);
        if (tid < NCELL - 256)
            sh[buf][tid + 256] = make_cell(cur.p1, cur.t1, cur.v1);
        __syncthreads();

        // Kick off next tile's global loads while we compute this one.
        const int tn = t + GRID;
        if (tn < total_tiles)
            cur = prefetch_tile(pred, target, tn, tid);

        const int r = t & 1023;
        const int ty0 = (r >> 5) << 4;
        const int tx0 = (r & 31) << 4;
        const int px = tid & 15;
        const int py = tid >> 4;

        const float4* base = &sh[buf][py * LW + px + HALO];
        const float4 ca = base[0];

        const h2 cay = hsp(ca.y), caz = pk2(ca.z, ca.z), caw = pk2(ca.w, ca.w);

        // self pair, fp32 scalar (j0 >= 0)
        const float j0 = ca.x * ca.x;
        const float u0 = __expf(-j0);
        const float L0 = fmaf(fmaf(fmaf(0.098765f, u0, -0.370370f), u0,
                                   0.962963f), u0, 0.004231f);
        const float m0 = fmaf(-j0, ca.y * ca.y, j0) + L0;
        const float gg0 = ca.z * ca.z;
        const float E0 = fmaf(fmaf(fmaf(-0.101088f, gg0, 0.454898f), gg0,
                                   -0.985612f), gg0, 0.998280f);
        const float d0 = m0 + E0;
        const float n0 = W_IN * ca.w;

        const FracH F1 = pair2h(ca.x, cay, caz, caw, base[1],          base[2],          mkh(W_IN,  W_OUT));
        const FracH F2 = pair2h(ca.x, cay, caz, caw, base[LW - 2],     base[LW - 1],     mkh(W_OUT, W_IN));
        const FracH F3 = pair2h(ca.x, cay, caz, caw, base[LW],         base[LW + 1],     mkh(W_IN,  W_IN));
        const FracH F4 = pair2h(ca.x, cay, caz, caw, base[LW + 2],     base[2 * LW - 2], mkh(W_OUT, W_OUT));
        const FracH F5 = pair2h(ca.x, cay, caz, caw, base[2 * LW - 1], base[2 * LW],     mkh(W_OUT, W_OUT));
        const FracH F6 = pair2h(ca.x, cay, caz, caw, base[2 * LW + 1], base[2 * LW + 2], mkh(W_OUT, W_OUT));

        const FracH A  = mergeh(F1, F2);
        const FracH Bb = mergeh(F3, F4);
        const FracH C  = mergeh(F5, F6);
        const FracH D2 = mergeh(A, Bb);
        const FracH G2 = mergeh(D2, C);

        const float nl = (float)G2.n.x, nh = (float)G2.n.y;
        const float dl = (float)G2.d.x, dh = (float)G2.d.y;
        const float Nt = fmaf(nl, dh, nh * dl), Dt = dl * dh;
        const float Nf = fmaf(n0, Dt, Nt * d0), Df = d0 * Dt;
        acc = fmaf(Nf, __builtin_amdgcn_rcpf(Df), acc);

        const bool edge = (tx0 == 0) | (tx0 == WD - TILE) | (ty0 == 0) | (ty0 == HT - TILE);
        if (edge) {
            const int gy = ty0 + py, gx = tx0 + px;
            #pragma unroll
            for (int k = 0; k < 12; ++k) {
                if (gy + pdy[k] >= HT || gx + pdx[k] < 0 || gx + pdx[k] >= WD)
                    acc += pw12[k] * (1.f - ca.w * INV_D_OOB);
                if (gy - pdy[k] < 0 || gx - pdx[k] < 0 || gx - pdx[k] >= WD)
                    acc += pw12[k];
            }
        }
        // No trailing barrier: next iteration writes the OTHER buffer, and the
        // write->read barrier above orders reuse two iterations apart.
    }

    // Fused reduction: wave shuffle -> cross-wave LDS (double) -> ONE fp32
    // atomic per block (pre-scaled). 2048 staggered atomics total.
    #pragma unroll
    for (int off = 32; off > 0; off >>= 1)
        acc += __shfl_down(acc, off, 64);
    __shared__ double wsum[4];
    if ((tid & 63) == 0) wsum[tid >> 6] = (double)acc;
    __syncthreads();
    if (tid == 0) {
        const double s = wsum[0] + wsum[1] + wsum[2] + wsum[3];
        atomicAdd(out, (float)(s * inv_cnt));
    }
}

extern "C" void kernel_launch(void* const* d_in, const int* in_sizes, int n_in,
                              void* d_out, int out_size, void* d_ws, size_t ws_size,
                              hipStream_t stream) {
    const float* pred   = (const float*)d_in[0];
    const float* target = (const float*)d_in[1];
    float* out = (float*)d_out;

    const int B = in_sizes[0] / (HT * WD);
    const int total_tiles = B * 1024;        // 16x16 tiles, 8192 for B=8

    (void)hipMemsetAsync(out, 0, sizeof(float), stream);
    scloss_main<<<GRID, 256, 0, stream>>>(pred, target, out, total_tiles,
                                          1.0 / ((double)B * HT * WD));
}

// Round 14
// 90.357 us; speedup vs baseline: 1.0678x; 1.0678x over previous
//
#include <hip/hip_runtime.h>

#define TILE 16
#define HALO 2
#define LH (TILE + HALO)        // 18 rows: tile + bottom halo (no top halo needed)
#define LW (TILE + 2 * HALO)    // 20 cols -> 360 cells
#define NCELL (LH * LW)
#define HT 512
#define WD 512
#define GRID 2048               // 8 blocks/CU x 256 CUs: fully resident, one batch

typedef _Float16 h2 __attribute__((ext_vector_type(2)));

constexpr float W_IN  = 1.0f / 9.0f + 0.02f;   // 3x3 ring: 1/9 + 0.5/25
constexpr float W_OUT = 0.02f;                 // 5x5 outer ring
// OOB cells staged as zeros -> d = L(1) + E(0) = 1.693869
constexpr float INV_D_OOB = 0.590364f;

__device__ __forceinline__ h2 pk2(float a, float b) {
    return __builtin_bit_cast(h2, __builtin_amdgcn_cvt_pkrtz(a, b));
}
__device__ __forceinline__ h2 hsp(float x) {
    h2 r; r.x = (_Float16)x; r.y = (_Float16)x; return r;
}
__device__ __forceinline__ h2 mkh(float a, float b) {
    h2 r; r.x = (_Float16)a; r.y = (_Float16)b; return r;
}

struct FracH { h2 n, d; };

// Two unordered-pair fractions vs common center, packed in half2 lanes.
// ln(1+u) deg-3 monomial (err<=4.2e-3); e^{-g} deg-3 monomial (err<=1.7e-3), eps folded.
__device__ __forceinline__ FracH pair2h(float cax, h2 cay, h2 caz, h2 caw,
                                        const float4 cb1, const float4 cb2, h2 wv) {
    const float j1 = cax * cb1.x, j2 = cax * cb2.x;
    const h2 J = pk2(j1, j2);
    const h2 U = pk2(__expf(-fabsf(j1)), __expf(-fabsf(j2)));
    const h2 T = pk2(cb1.y, cb2.y);
    const h2 G = pk2(cb1.z, cb2.z);
    const h2 Wb = pk2(cb1.w, cb2.w);
    h2 L = __builtin_elementwise_fma(U, hsp(0.098765f), hsp(-0.370370f));
    L = __builtin_elementwise_fma(L, U, hsp(0.962963f));
    L = __builtin_elementwise_fma(L, U, hsp(0.004231f));
    const h2 LAB = T * cay;
    const h2 mx = __builtin_elementwise_max(J, hsp(0.f));
    h2 m = __builtin_elementwise_fma(-J, LAB, mx);
    m = m + L;
    const h2 GG = G * caz;
    h2 E = __builtin_elementwise_fma(GG, hsp(-0.101088f), hsp(0.454898f));
    E = __builtin_elementwise_fma(E, GG, hsp(-0.985612f));
    E = __builtin_elementwise_fma(E, GG, hsp(0.998280f));
    FracH r;
    r.d = m + E;
    r.n = (Wb + caw) * wv;
    return r;
}

__device__ __forceinline__ FracH mergeh(FracH a, FracH b) {
    FracH r;
    r.n = __builtin_elementwise_fma(a.n, b.d, a.d * b.n);
    r.d = a.d * b.d;
    return r;
}

struct Pre { float p0, t0, p1, t1; bool v0, v1; };

__device__ __forceinline__ Pre prefetch_tile(const float* __restrict__ pred,
                                             const float* __restrict__ targ,
                                             int t, int tid) {
    const int b = t >> 10;
    const int r = t & 1023;
    const int ty0 = (r >> 5) << 4;
    const int tx0 = (r & 31) << 4;
    const float* pb = pred + ((size_t)b << 18);
    const float* tb = targ + ((size_t)b << 18);
    Pre o; o.p0 = 0.f; o.t0 = 0.f; o.p1 = 0.f; o.t1 = 0.f;
    {   // slot 0: cell idx = tid (tid < 256 < 360)
        const int cy = tid / LW, cx = tid - cy * LW;
        const int gy = ty0 + cy, gx = tx0 + cx - HALO;
        o.v0 = ((unsigned)gx < (unsigned)WD) && (gy < HT);
        if (o.v0) { const int gi = (gy << 9) + gx; o.p0 = pb[gi]; o.t0 = tb[gi]; }
    }
    {   // slot 1: cell idx = tid + 256 (only tid < 104)
        const int idx = tid + 256;
        const int cy = idx / LW, cx = idx - cy * LW;
        const int gy = ty0 + cy, gx = tx0 + cx - HALO;
        o.v1 = (idx < NCELL) && ((unsigned)gx < (unsigned)WD) && (gy < HT);
        if (o.v1) { const int gi = (gy << 9) + gx; o.p1 = pb[gi]; o.t1 = tb[gi]; }
    }
    return o;
}

__device__ __forceinline__ float4 make_cell(float p, float t, bool valid) {
    float4 c = make_float4(0.f, 0.f, 0.f, 0.f);
    if (valid) {
        const float en = __expf(-fabsf(p));
        const float inv = __builtin_amdgcn_rcpf(1.f + en);
        const float g = (p >= 0.f) ? inv : en * inv;          // sigmoid(p)
        const float L = fmaf(fmaf(fmaf(0.098765f, en, -0.370370f), en,
                                  0.962963f), en, 0.004231f);
        const float bce = fmaf(-p, t, fmaxf(p, 0.f)) + L;
        c = make_float4(p, t, g, bce);
    }
    return c;
}

__global__ __launch_bounds__(256) void scloss_main(
    const float* __restrict__ pred, const float* __restrict__ target,
    double* __restrict__ partial, int total_tiles) {
    __shared__ float4 sh[2][NCELL];   // double buffer

    const int tid = threadIdx.x;
    float acc = 0.f;

    constexpr int pdy[12] = {0, 0, 1, 1, 1, 1, 1, 2, 2, 2, 2, 2};
    constexpr int pdx[12] = {1, 2, -2, -1, 0, 1, 2, -2, -1, 0, 1, 2};
    constexpr float pw12[12] = {W_IN, W_OUT, W_OUT, W_IN, W_IN, W_IN,
                                W_OUT, W_OUT, W_OUT, W_OUT, W_OUT, W_OUT};

    Pre cur = prefetch_tile(pred, target, blockIdx.x, tid);

    int buf = 0;
    for (int t = blockIdx.x; t < total_tiles; t += GRID, buf ^= 1) {
        // Stage current tile from prefetched registers.
        sh[buf][tid] = make_cell(cur.p0, cur.t0, cur.v0);
        if (tid < NCELL - 256)
            sh[buf][tid + 256] = make_cell(cur.p1, cur.t1, cur.v1);
        __syncthreads();

        // Kick off next tile's global loads while we compute this one.
        const int tn = t + GRID;
        if (tn < total_tiles)
            cur = prefetch_tile(pred, target, tn, tid);

        const int r = t & 1023;
        const int ty0 = (r >> 5) << 4;
        const int tx0 = (r & 31) << 4;
        const int px = tid & 15;
        const int py = tid >> 4;

        const float4* base = &sh[buf][py * LW + px + HALO];
        const float4 ca = base[0];

        const h2 cay = hsp(ca.y), caz = pk2(ca.z, ca.z), caw = pk2(ca.w, ca.w);

        // self pair, fp32 scalar (j0 >= 0)
        const float j0 = ca.x * ca.x;
        const float u0 = __expf(-j0);
        const float L0 = fmaf(fmaf(fmaf(0.098765f, u0, -0.370370f), u0,
                                   0.962963f), u0, 0.004231f);
        const float m0 = fmaf(-j0, ca.y * ca.y, j0) + L0;
        const float gg0 = ca.z * ca.z;
        const float E0 = fmaf(fmaf(fmaf(-0.101088f, gg0, 0.454898f), gg0,
                                   -0.985612f), gg0, 0.998280f);
        const float d0 = m0 + E0;
        const float n0 = W_IN * ca.w;

        const FracH F1 = pair2h(ca.x, cay, caz, caw, base[1],          base[2],          mkh(W_IN,  W_OUT));
        const FracH F2 = pair2h(ca.x, cay, caz, caw, base[LW - 2],     base[LW - 1],     mkh(W_OUT, W_IN));
        const FracH F3 = pair2h(ca.x, cay, caz, caw, base[LW],         base[LW + 1],     mkh(W_IN,  W_IN));
        const FracH F4 = pair2h(ca.x, cay, caz, caw, base[LW + 2],     base[2 * LW - 2], mkh(W_OUT, W_OUT));
        const FracH F5 = pair2h(ca.x, cay, caz, caw, base[2 * LW - 1], base[2 * LW],     mkh(W_OUT, W_OUT));
        const FracH F6 = pair2h(ca.x, cay, caz, caw, base[2 * LW + 1], base[2 * LW + 2], mkh(W_OUT, W_OUT));

        const FracH A  = mergeh(F1, F2);
        const FracH Bb = mergeh(F3, F4);
        const FracH C  = mergeh(F5, F6);
        const FracH D2 = mergeh(A, Bb);
        const FracH G2 = mergeh(D2, C);

        const float nl = (float)G2.n.x, nh = (float)G2.n.y;
        const float dl = (float)G2.d.x, dh = (float)G2.d.y;
        const float Nt = fmaf(nl, dh, nh * dl), Dt = dl * dh;
        const float Nf = fmaf(n0, Dt, Nt * d0), Df = d0 * Dt;
        acc = fmaf(Nf, __builtin_amdgcn_rcpf(Df), acc);

        const bool edge = (tx0 == 0) | (tx0 == WD - TILE) | (ty0 == 0) | (ty0 == HT - TILE);
        if (edge) {
            const int gy = ty0 + py, gx = tx0 + px;
            #pragma unroll
            for (int k = 0; k < 12; ++k) {
                if (gy + pdy[k] >= HT || gx + pdx[k] < 0 || gx + pdx[k] >= WD)
                    acc += pw12[k] * (1.f - ca.w * INV_D_OOB);
                if (gy - pdy[k] < 0 || gx - pdx[k] < 0 || gx - pdx[k] >= WD)
                    acc += pw12[k];
            }
        }
        // No trailing barrier: next iteration writes the OTHER buffer, and the
        // write->read barrier above orders reuse two iterations apart.
    }

    // Wave shuffle reduction; one partial per wave (4/block), no extra barrier.
    #pragma unroll
    for (int off = 32; off > 0; off >>= 1)
        acc += __shfl_down(acc, off, 64);
    if ((tid & 63) == 0)
        partial[(blockIdx.x << 2) | (tid >> 6)] = (double)acc;
}

__global__ __launch_bounds__(256) void scloss_reduce(
    const double* __restrict__ partial, int n, float* __restrict__ out,
    double inv_cnt) {
    __shared__ double sm[256];
    double s = 0.0;
    for (int i = threadIdx.x; i < n; i += 256) s += partial[i];
    sm[threadIdx.x] = s;
    __syncthreads();
    for (int off = 128; off > 0; off >>= 1) {
        if (threadIdx.x < off) sm[threadIdx.x] += sm[threadIdx.x + off];
        __syncthreads();
    }
    if (threadIdx.x == 0) out[0] = (float)(sm[0] * inv_cnt);
}

extern "C" void kernel_launch(void* const* d_in, const int* in_sizes, int n_in,
                              void* d_out, int out_size, void* d_ws, size_t ws_size,
                              hipStream_t stream) {
    const float* pred   = (const float*)d_in[0];
    const float* target = (const float*)d_in[1];
    float* out = (float*)d_out;

    const int B = in_sizes[0] / (HT * WD);
    const int total_tiles = B * 1024;        // 16x16 tiles, 8192 for B=8

    double* partial = (double*)d_ws;
    scloss_main<<<GRID, 256, 0, stream>>>(pred, target, partial, total_tiles);
    scloss_reduce<<<1, 256, 0, stream>>>(partial, GRID * 4, out,
                                         1.0 / ((double)B * HT * WD));
}